// Round 7
// baseline (210.259 us; speedup 1.0000x reference)
//
#include <hip/hip_runtime.h>
#include <hip/hip_bf16.h>

// KAN harmonic-basis GEMM, v10: K-split-2 + tall waves + global_load_lds staging.
// out[b,h] = sum_{d,f} basis(x[b,d])[f] * W[d,f,h] + sum_d b[d,h]
//
// f=0 + bias -> fp32 partials c_part[8][256], summed in GEMM epilogue.
// f=1..10    -> bf16 MFMA GEMM, M=16384, N=256, K=2560.
//
// v10 (v9 post-mortem: 1-i waves do 1 LDS read per MFMA -> 25us LDS-pipe
// busy/CU, eating the occupancy gain; v8's 2-i waves need only 12.5us but
// its 256-thr grid caps at 2 waves/SIMD):
//   - 512-thread blocks, SAME BM=64 x BN=128 tile (grid 512 -> 2 blocks/CU,
//     4 waves/SIMD). 8 waves = kh(2, K-half) x wr(2) x wc(2); each wave:
//     32 rows (2 i-frags) x 64 cols (4 j-frags) x 40 kt (its K-half).
//     Conserves v8's per-CU totals (trig dup 4, 1.31MB B-DMA, 12.5us LDS
//     reads) at DOUBLE the occupancy.
//   - 20 phases x 4 kt (2 kt per K-half); LDS 2 x 32KB. Stage issued a full
//     phase ahead via global_load_lds (v8-proven, compiler can't shallow it).
//   - End: K-half-1 waves pass acc through 32KB LDS (reuse Bs) to half-0
//     partners; 2 extra barriers.
//   - VGPR: v8 measured 92 for this same compute structure (v6's 200-reg
//     blowup was the register B-ring, gone here) -> 128 cap is safe.

#define BDIM 16384
#define DDIM 256
#define HOUT 256
#define NKT  80
#define BM 64
#define BN 128

typedef __bf16 bf16x8 __attribute__((ext_vector_type(8)));
typedef float floatx4 __attribute__((ext_vector_type(4)));

__device__ __forceinline__ unsigned short f2bf(float f) {
    unsigned int u = __float_as_uint(f);
    return (unsigned short)((u + 0x7FFFu + ((u >> 16) & 1u)) >> 16);
}

__device__ __forceinline__ unsigned int pkbf(float a, float b) {
    __hip_bfloat162 r = __float22bfloat162_rn(make_float2(a, b));
    return *reinterpret_cast<unsigned int*>(&r);
}

// grid 328 x 256 threads.
// blocks [0,320): kt = bid>>2, sub = bid&3:
//   Wfrag[kt][n=t][dd = sub*8 .. +8] = bf16(W[dtile*32+dd][kt%10+1][n])
// blocks [320,328): p = bid-320; c_part[p][h] = sum_{d in p*32..+32} W[d][0][h]+b[d][h]
__global__ void prep_kernel(const float* __restrict__ W, const float* __restrict__ bias,
                            unsigned short* __restrict__ Wfrag, float* __restrict__ c_part) {
    const int bid = blockIdx.x;
    const int t = threadIdx.x;
    if (bid < 4 * NKT) {
        const int kt = bid >> 2;
        const int sub = bid & 3;
        const int dtile = kt / 10;
        const int f = kt - dtile * 10 + 1;
        const int d0 = dtile * 32 + sub * 8;
        const float* wsrc = W + ((size_t)d0 * 11 + f) * 256 + t;
        union { unsigned short s[8]; int4 v; } buf;
#pragma unroll
        for (int dd = 0; dd < 8; ++dd)
            buf.s[dd] = f2bf(wsrc[(size_t)dd * 11 * 256]);
        *(int4*)(Wfrag + ((size_t)kt * 256 + t) * 32 + sub * 8) = buf.v;
    } else {
        const int p = bid - 4 * NKT;
        float acc = 0.f;
#pragma unroll
        for (int dd = 0; dd < 32; ++dd) {
            const int d = p * 32 + dd;
            acc += W[(size_t)(d * 11) * 256 + t] + bias[(size_t)d * 256 + t];
        }
        c_part[p * 256 + t] = acc;
    }
}

// Stage one phase (2 kt per K-half, 32 KB) into lbuf. Chunk c in [0,32):
// kh_c = c>>4, ktl = (c>>3)&1, f = c&7 (16 cols). Global kt = kh_c*40 +
// ph*2 + ktl. LDS dest linear (chunk*1024 + lane*16B); per-lane global source
// puts lane slot l at (col l&15, dgroup l>>4) -- the MFMA B-frag this lane
// reads back. 8 waves x 4 chunks each.
__device__ __forceinline__ void stage_phase(const unsigned short* __restrict__ Wfrag,
                                            unsigned short* lbuf, int ph,
                                            int h0, int wave, int l15, int koff) {
#pragma unroll
    for (int s = 0; s < 4; ++s) {
        const int c = wave * 4 + s;
        const int kh_c = c >> 4;
        const int ktl = (c >> 3) & 1;
        const int f = c & 7;
        const int ktg = kh_c * 40 + ph * 2 + ktl;
        const unsigned short* g = Wfrag + (size_t)ktg * 8192
                                + (h0 + f * 16 + l15) * 32 + koff * 8;
        __builtin_amdgcn_global_load_lds((const void*)g, (void*)(lbuf + c * 512), 16, 0, 0);
    }
}

__global__ __launch_bounds__(512, 4)
void kan_gemm(const float* __restrict__ x, const unsigned short* __restrict__ Wfrag,
              const float* __restrict__ c_part, float* __restrict__ out) {
    __shared__ unsigned short Bs[2][4 * 8 * 512];   // 2 x 32,768 B -> 2 blocks/CU

    const int t = threadIdx.x;
    const int m0 = blockIdx.x * BM;
    const int h0 = blockIdx.y * BN;

    const int lane = t & 63;
    const int wave = t >> 6;         // 0..7
    const int kh = wave >> 2;        // K-half: dtiles kh*4 .. +4 (kt kh*40..+40)
    const int wq = wave & 3;
    const int wr = wq >> 1;          // row half (32 rows)
    const int wc = wq & 1;           // col half (64 cols)
    const int l15 = lane & 15;
    const int koff = lane >> 4;

    floatx4 acc[2][4];
#pragma unroll
    for (int i = 0; i < 2; ++i)
#pragma unroll
        for (int j = 0; j < 4; ++j)
            acc[i][j] = (floatx4){0.f, 0.f, 0.f, 0.f};

    // lane's x rows: i=0 -> m0 + wr*32 + l15, i=1 -> +16; d: koff*8 + kh*128
    const float* xr0 = x + (size_t)(m0 + wr * 32 + l15) * DDIM + koff * 8 + kh * 128;

    // x for this half's dtile 0
    float4 xn[4];
    xn[0] = *(const float4*)(xr0 + 0);
    xn[1] = *(const float4*)(xr0 + 4);
    xn[2] = *(const float4*)(xr0 + 16 * DDIM + 0);
    xn[3] = *(const float4*)(xr0 + 16 * DDIM + 4);

    // prologue: stage phase 0 into Bs[0]
    stage_phase(Wfrag, &Bs[0][0], 0, h0, wave, l15, koff);
    __syncthreads();

    // Chebyshev state persists across the 5 phases of a dtile
    float sc[16], cc[16], sp[16], cp[16], t2c[16];

#pragma unroll
    for (int ph = 0; ph < 20; ++ph) {
        const int buf = ph & 1;

        // issue next phase's stage into the other buffer (spans this phase)
        if (ph < 19)
            stage_phase(Wfrag, &Bs[buf ^ 1][0], ph + 1, h0, wave, l15, koff);

        if (ph % 5 == 0) {
            // ---- dtile start: sincos of 16 elems; Chebyshev init ----
#pragma unroll
            for (int i = 0; i < 2; ++i)
#pragma unroll
                for (int e = 0; e < 8; ++e) {
                    const int g = i * 8 + e;
                    const float xv = ((const float*)&xn[i * 2 + (e >> 2)])[e & 3];
                    __sincosf(xv, &sc[g], &cc[g]);
                    t2c[g] = cc[g] + cc[g];
                    sp[g] = 0.f;
                    cp[g] = 1.f;
                }
        }

        // ---- compute 2 kt of this phase (this K-half's slice) ----
#pragma unroll
        for (int s = 0; s < 2; ++s) {
            const int hs = (ph * 2 + s) % 10;         // 0..9 within dtile
            const float* src = (hs & 1) ? cc : sc;    // even: sin(kx), odd: cos(kx)

            union { unsigned int u[4]; bf16x8 v; } a0, a1;
#pragma unroll
            for (int q = 0; q < 4; ++q) {
                a0.u[q] = pkbf(src[2 * q], src[2 * q + 1]);
                a1.u[q] = pkbf(src[8 + 2 * q], src[8 + 2 * q + 1]);
            }

            const unsigned short* fb = &Bs[buf][((kh * 2 + s) * 8 + wc * 4) * 512 + lane * 8];
            const bf16x8 b0 = *(const bf16x8*)(fb);
            const bf16x8 b1 = *(const bf16x8*)(fb + 512);
            const bf16x8 b2 = *(const bf16x8*)(fb + 1024);
            const bf16x8 b3 = *(const bf16x8*)(fb + 1536);

            acc[0][0] = __builtin_amdgcn_mfma_f32_16x16x32_bf16(a0.v, b0, acc[0][0], 0, 0, 0);
            acc[1][0] = __builtin_amdgcn_mfma_f32_16x16x32_bf16(a1.v, b0, acc[1][0], 0, 0, 0);
            acc[0][1] = __builtin_amdgcn_mfma_f32_16x16x32_bf16(a0.v, b1, acc[0][1], 0, 0, 0);
            acc[1][1] = __builtin_amdgcn_mfma_f32_16x16x32_bf16(a1.v, b1, acc[1][1], 0, 0, 0);
            acc[0][2] = __builtin_amdgcn_mfma_f32_16x16x32_bf16(a0.v, b2, acc[0][2], 0, 0, 0);
            acc[1][2] = __builtin_amdgcn_mfma_f32_16x16x32_bf16(a1.v, b2, acc[1][2], 0, 0, 0);
            acc[0][3] = __builtin_amdgcn_mfma_f32_16x16x32_bf16(a0.v, b3, acc[0][3], 0, 0, 0);
            acc[1][3] = __builtin_amdgcn_mfma_f32_16x16x32_bf16(a1.v, b3, acc[1][3], 0, 0, 0);

            // advance harmonic after each cos emit (except the last)
            if ((hs & 1) && hs < 9) {
#pragma unroll
                for (int g = 0; g < 16; ++g) {
                    const float ns = t2c[g] * sc[g] - sp[g];
                    const float nc = t2c[g] * cc[g] - cp[g];
                    sp[g] = sc[g]; cp[g] = cc[g];
                    sc[g] = ns;   cc[g] = nc;
                }
            }
        }

        // x prefetch for the next dtile, mid-dtile (phases 2,7,12)
        if (ph % 5 == 2 && ph < 15) {
            const int dn = ph / 5 + 1;
            xn[0] = *(const float4*)(xr0 + dn * 32 + 0);
            xn[1] = *(const float4*)(xr0 + dn * 32 + 4);
            xn[2] = *(const float4*)(xr0 + 16 * DDIM + dn * 32 + 0);
            xn[3] = *(const float4*)(xr0 + 16 * DDIM + dn * 32 + 4);
        }

        __syncthreads();   // drains stage loads (issued a full phase ago) + swap
    }

    // ---- cross-half combine via LDS (reuse Bs: 32 KB needed) ----
    float* red = (float*)&Bs[0][0];   // [wq][i][j][lane*4] = ((wq*2+i)*4+j)*256
    if (kh == 1) {
#pragma unroll
        for (int i = 0; i < 2; ++i)
#pragma unroll
            for (int j = 0; j < 4; ++j)
                *(floatx4*)&red[(((wq * 2 + i) * 4 + j) * 256) + lane * 4] = acc[i][j];
    }
    __syncthreads();

    if (kh == 0) {
        // bias partials
        float cj[4];
#pragma unroll
        for (int j = 0; j < 4; ++j) {
            const int col = h0 + wc * 64 + j * 16 + l15;
            float s = 0.f;
#pragma unroll
            for (int q = 0; q < 8; ++q) s += c_part[q * 256 + col];
            cj[j] = s;
        }
        // epilogue: C/D layout col=lane&15, row=(lane>>4)*4+reg
#pragma unroll
        for (int i = 0; i < 2; ++i) {
            const int row0 = m0 + wr * 32 + i * 16 + koff * 4;
#pragma unroll
            for (int j = 0; j < 4; ++j) {
                const int col = h0 + wc * 64 + j * 16 + l15;
                const floatx4 v = *(const floatx4*)&red[(((wq * 2 + i) * 4 + j) * 256) + lane * 4];
#pragma unroll
                for (int r = 0; r < 4; ++r)
                    out[(size_t)(row0 + r) * HOUT + col] = acc[i][j][r] + v[r] + cj[j];
            }
        }
    }
}

extern "C" void kernel_launch(void* const* d_in, const int* in_sizes, int n_in,
                              void* d_out, int out_size, void* d_ws, size_t ws_size,
                              hipStream_t stream) {
    const float* x = (const float*)d_in[0];
    const float* W = (const float*)d_in[1];
    const float* b = (const float*)d_in[2];
    float* out = (float*)d_out;

    unsigned short* Wfrag = (unsigned short*)d_ws;                      // 1,310,720 B
    float* c_part = (float*)((char*)d_ws + (size_t)NKT * 256 * 32 * 2); // 8 KB

    prep_kernel<<<4 * NKT + 8, 256, 0, stream>>>(W, b, Wfrag, c_part);
    kan_gemm<<<dim3(BDIM / BM, HOUT / BN), 512, 0, stream>>>(x, Wfrag, c_part, out);
}

// Round 8
// 108.399 us; speedup vs baseline: 1.9397x; 1.9397x over previous
//
#include <hip/hip_runtime.h>
#include <hip/hip_bf16.h>
#include <hip/hip_fp16.h>

// KAN harmonic-basis GEMM, v11: K-split-2 tall waves, fp16-packed trig state
// to fit the 128-VGPR budget that 4 waves/SIMD requires.
// out[b,h] = sum_{d,f} basis(x[b,d])[f] * W[d,f,h] + sum_d b[d,h]
//
// f=0 + bias -> fp32 partials c_part[8][256], summed in GEMM epilogue.
// f=1..10    -> bf16 MFMA GEMM, M=16384, N=256, K=2560.
//
// v11 (v10 post-mortem: f32 trig state (64-80 regs) + acc(32) + temps
// cannot fit 128 regs -> spill cascade, WRITE_SIZE 321MB. v9: 1-i waves
// double LDS-read pipe to ~17-25us. v8: 2-i at 2 waves/SIMD = latency-bound
// 45.7us):
//   - SAME v10 structure (correctness-verified): 512-thr blocks, BM=64 x
//     BN=128, 8 waves = kh(2) x wr(2) x wc(2), each 32 rows x 64 cols x
//     half-K; 20 phases x (2 kt per half); LDS 2 x 32KB double buffer staged
//     via global_load_lds one phase ahead; LDS cross-half combine at end.
//   - Trig state packed fp16: s1,c1,sk,ck as half2[8] = 32 VGPR (was 64-80
//     f32). Angle-addition advance via __hfma2. Init sincos still f32.
//     Error ~2^-11 * sqrt(2)^4 ~ 0.003 < bf16 pack rounding already present;
//     absmax threshold 1.165 has ample headroom.
//   - Pack path: half2 -> float2 -> v_cvt_pk_bf16_f32. Explicit if(hs&1)
//     branch (compile-time) instead of array-pointer select.
//   - x reloaded at dtile start (no reg prefetch): saves 16 live regs;
//     L2-hot, amortized over 5 phases, covered by co-resident block.
//   - Working set ~110-124 <= 128. Kill signal: WRITE_SIZE >> 16.4MB again.

#define BDIM 16384
#define DDIM 256
#define HOUT 256
#define NKT  80
#define BM 64
#define BN 128

typedef __bf16 bf16x8 __attribute__((ext_vector_type(8)));
typedef float floatx4 __attribute__((ext_vector_type(4)));

__device__ __forceinline__ unsigned short f2bf(float f) {
    unsigned int u = __float_as_uint(f);
    return (unsigned short)((u + 0x7FFFu + ((u >> 16) & 1u)) >> 16);
}

__device__ __forceinline__ unsigned int pkbf(float a, float b) {
    __hip_bfloat162 r = __float22bfloat162_rn(make_float2(a, b));
    return *reinterpret_cast<unsigned int*>(&r);
}

__device__ __forceinline__ unsigned int pk_h2_bf(__half2 h) {
    const float2 f = __half22float2(h);
    return pkbf(f.x, f.y);
}

// grid 328 x 256 threads.
// blocks [0,320): kt = bid>>2, sub = bid&3:
//   Wfrag[kt][n=t][dd = sub*8 .. +8] = bf16(W[dtile*32+dd][kt%10+1][n])
// blocks [320,328): p = bid-320; c_part[p][h] = sum_{d in p*32..+32} W[d][0][h]+b[d][h]
__global__ void prep_kernel(const float* __restrict__ W, const float* __restrict__ bias,
                            unsigned short* __restrict__ Wfrag, float* __restrict__ c_part) {
    const int bid = blockIdx.x;
    const int t = threadIdx.x;
    if (bid < 4 * NKT) {
        const int kt = bid >> 2;
        const int sub = bid & 3;
        const int dtile = kt / 10;
        const int f = kt - dtile * 10 + 1;
        const int d0 = dtile * 32 + sub * 8;
        const float* wsrc = W + ((size_t)d0 * 11 + f) * 256 + t;
        union { unsigned short s[8]; int4 v; } buf;
#pragma unroll
        for (int dd = 0; dd < 8; ++dd)
            buf.s[dd] = f2bf(wsrc[(size_t)dd * 11 * 256]);
        *(int4*)(Wfrag + ((size_t)kt * 256 + t) * 32 + sub * 8) = buf.v;
    } else {
        const int p = bid - 4 * NKT;
        float acc = 0.f;
#pragma unroll
        for (int dd = 0; dd < 32; ++dd) {
            const int d = p * 32 + dd;
            acc += W[(size_t)(d * 11) * 256 + t] + bias[(size_t)d * 256 + t];
        }
        c_part[p * 256 + t] = acc;
    }
}

// Stage one phase (2 kt per K-half, 32 KB) into lbuf. Chunk c in [0,32):
// kh_c = c>>4, ktl = (c>>3)&1, f = c&7 (16 cols). Global kt = kh_c*40 +
// ph*2 + ktl. LDS dest linear (chunk*1024 + lane*16B); per-lane global source
// puts lane slot l at (col l&15, dgroup l>>4) -- the MFMA B-frag this lane
// reads back. 8 waves x 4 chunks each.
__device__ __forceinline__ void stage_phase(const unsigned short* __restrict__ Wfrag,
                                            unsigned short* lbuf, int ph,
                                            int h0, int wave, int l15, int koff) {
#pragma unroll
    for (int s = 0; s < 4; ++s) {
        const int c = wave * 4 + s;
        const int kh_c = c >> 4;
        const int ktl = (c >> 3) & 1;
        const int f = c & 7;
        const int ktg = kh_c * 40 + ph * 2 + ktl;
        const unsigned short* g = Wfrag + (size_t)ktg * 8192
                                + (h0 + f * 16 + l15) * 32 + koff * 8;
        __builtin_amdgcn_global_load_lds((const void*)g, (void*)(lbuf + c * 512), 16, 0, 0);
    }
}

__global__ __launch_bounds__(512, 4)
void kan_gemm(const float* __restrict__ x, const unsigned short* __restrict__ Wfrag,
              const float* __restrict__ c_part, float* __restrict__ out) {
    __shared__ unsigned short Bs[2][4 * 8 * 512];   // 2 x 32,768 B

    const int t = threadIdx.x;
    const int m0 = blockIdx.x * BM;
    const int h0 = blockIdx.y * BN;

    const int lane = t & 63;
    const int wave = t >> 6;         // 0..7
    const int kh = wave >> 2;        // K-half: kt kh*40 .. +40
    const int wq = wave & 3;
    const int wr = wq >> 1;          // row half (32 rows)
    const int wc = wq & 1;           // col half (64 cols)
    const int l15 = lane & 15;
    const int koff = lane >> 4;

    floatx4 acc[2][4];
#pragma unroll
    for (int i = 0; i < 2; ++i)
#pragma unroll
        for (int j = 0; j < 4; ++j)
            acc[i][j] = (floatx4){0.f, 0.f, 0.f, 0.f};

    // lane's x rows: i=0 -> m0 + wr*32 + l15, i=1 -> +16; d: koff*8 + kh*128
    const float* xr0 = x + (size_t)(m0 + wr * 32 + l15) * DDIM + koff * 8 + kh * 128;

    // prologue: stage phase 0 into Bs[0]
    stage_phase(Wfrag, &Bs[0][0], 0, h0, wave, l15, koff);
    __syncthreads();

    // fp16-packed trig state: pair p holds elems {2p, 2p+1};
    // p 0..3 -> i=0 (d-slots koff*8 + 0..7), p 4..7 -> i=1.
    __half2 s1h[8], c1h[8], skh[8], ckh[8];

#pragma unroll
    for (int ph = 0; ph < 20; ++ph) {
        const int buf = ph & 1;

        // issue next phase's stage into the other buffer (spans this phase)
        if (ph < 19)
            stage_phase(Wfrag, &Bs[buf ^ 1][0], ph + 1, h0, wave, l15, koff);

        if (ph % 5 == 0) {
            // ---- dtile start: load x (L2-hot), sincos f32, pack fp16 ----
            const int dt = ph / 5;
#pragma unroll
            for (int i = 0; i < 2; ++i) {
                const float4 xa = *(const float4*)(xr0 + i * 16 * DDIM + dt * 32 + 0);
                const float4 xb = *(const float4*)(xr0 + i * 16 * DDIM + dt * 32 + 4);
                const float xv[8] = {xa.x, xa.y, xa.z, xa.w, xb.x, xb.y, xb.z, xb.w};
#pragma unroll
                for (int p = 0; p < 4; ++p) {
                    float s0, c0, s1, c1;
                    __sincosf(xv[2 * p], &s0, &c0);
                    __sincosf(xv[2 * p + 1], &s1, &c1);
                    const __half2 sh = __floats2half2_rn(s0, s1);
                    const __half2 ch = __floats2half2_rn(c0, c1);
                    s1h[i * 4 + p] = sh;
                    c1h[i * 4 + p] = ch;
                    skh[i * 4 + p] = sh;
                    ckh[i * 4 + p] = ch;
                }
            }
        }

        // ---- compute 2 kt of this phase (this K-half's slice) ----
#pragma unroll
        for (int s = 0; s < 2; ++s) {
            const int hs = (ph * 2 + s) % 10;         // 0..9 within dtile

            union { unsigned int u[4]; bf16x8 v; } a0, a1;
            if (hs & 1) {   // cos(kx)
#pragma unroll
                for (int q = 0; q < 4; ++q) {
                    a0.u[q] = pk_h2_bf(ckh[q]);
                    a1.u[q] = pk_h2_bf(ckh[q + 4]);
                }
            } else {        // sin(kx)
#pragma unroll
                for (int q = 0; q < 4; ++q) {
                    a0.u[q] = pk_h2_bf(skh[q]);
                    a1.u[q] = pk_h2_bf(skh[q + 4]);
                }
            }

            const unsigned short* fb = &Bs[buf][((kh * 2 + s) * 8 + wc * 4) * 512 + lane * 8];
            const bf16x8 b0 = *(const bf16x8*)(fb);
            const bf16x8 b1 = *(const bf16x8*)(fb + 512);
            const bf16x8 b2 = *(const bf16x8*)(fb + 1024);
            const bf16x8 b3 = *(const bf16x8*)(fb + 1536);

            acc[0][0] = __builtin_amdgcn_mfma_f32_16x16x32_bf16(a0.v, b0, acc[0][0], 0, 0, 0);
            acc[1][0] = __builtin_amdgcn_mfma_f32_16x16x32_bf16(a1.v, b0, acc[1][0], 0, 0, 0);
            acc[0][1] = __builtin_amdgcn_mfma_f32_16x16x32_bf16(a0.v, b1, acc[0][1], 0, 0, 0);
            acc[1][1] = __builtin_amdgcn_mfma_f32_16x16x32_bf16(a1.v, b1, acc[1][1], 0, 0, 0);
            acc[0][2] = __builtin_amdgcn_mfma_f32_16x16x32_bf16(a0.v, b2, acc[0][2], 0, 0, 0);
            acc[1][2] = __builtin_amdgcn_mfma_f32_16x16x32_bf16(a1.v, b2, acc[1][2], 0, 0, 0);
            acc[0][3] = __builtin_amdgcn_mfma_f32_16x16x32_bf16(a0.v, b3, acc[0][3], 0, 0, 0);
            acc[1][3] = __builtin_amdgcn_mfma_f32_16x16x32_bf16(a1.v, b3, acc[1][3], 0, 0, 0);

            // advance harmonic k -> k+1 after each cos emit (except hs=9):
            // ns = sk*c1 + ck*s1 ; nc = ck*c1 - sk*s1   (packed fp16)
            if ((hs & 1) && hs < 9) {
#pragma unroll
                for (int p = 0; p < 8; ++p) {
                    const __half2 t0 = __hmul2(skh[p], c1h[p]);
                    const __half2 t1 = __hmul2(skh[p], s1h[p]);
                    const __half2 ns = __hfma2(ckh[p], s1h[p], t0);
                    const __half2 nc = __hfma2(ckh[p], c1h[p], __hneg2(t1));
                    skh[p] = ns;
                    ckh[p] = nc;
                }
            }
        }

        __syncthreads();   // drains stage loads (issued a full phase ago) + swap
    }

    // ---- cross-half combine via LDS (reuse Bs: 32 KB needed) ----
    float* red = (float*)&Bs[0][0];   // [wq][i][j][lane*4]
    if (kh == 1) {
#pragma unroll
        for (int i = 0; i < 2; ++i)
#pragma unroll
            for (int j = 0; j < 4; ++j)
                *(floatx4*)&red[(((wq * 2 + i) * 4 + j) * 256) + lane * 4] = acc[i][j];
    }
    __syncthreads();

    if (kh == 0) {
        // bias partials
        float cj[4];
#pragma unroll
        for (int j = 0; j < 4; ++j) {
            const int col = h0 + wc * 64 + j * 16 + l15;
            float s = 0.f;
#pragma unroll
            for (int q = 0; q < 8; ++q) s += c_part[q * 256 + col];
            cj[j] = s;
        }
        // epilogue: C/D layout col=lane&15, row=(lane>>4)*4+reg
#pragma unroll
        for (int i = 0; i < 2; ++i) {
            const int row0 = m0 + wr * 32 + i * 16 + koff * 4;
#pragma unroll
            for (int j = 0; j < 4; ++j) {
                const int col = h0 + wc * 64 + j * 16 + l15;
                const floatx4 v = *(const floatx4*)&red[(((wq * 2 + i) * 4 + j) * 256) + lane * 4];
#pragma unroll
                for (int r = 0; r < 4; ++r)
                    out[(size_t)(row0 + r) * HOUT + col] = acc[i][j][r] + v[r] + cj[j];
            }
        }
    }
}

extern "C" void kernel_launch(void* const* d_in, const int* in_sizes, int n_in,
                              void* d_out, int out_size, void* d_ws, size_t ws_size,
                              hipStream_t stream) {
    const float* x = (const float*)d_in[0];
    const float* W = (const float*)d_in[1];
    const float* b = (const float*)d_in[2];
    float* out = (float*)d_out;

    unsigned short* Wfrag = (unsigned short*)d_ws;                      // 1,310,720 B
    float* c_part = (float*)((char*)d_ws + (size_t)NKT * 256 * 32 * 2); // 8 KB

    prep_kernel<<<4 * NKT + 8, 256, 0, stream>>>(W, b, Wfrag, c_part);
    kan_gemm<<<dim3(BDIM / BM, HOUT / BN), 512, 0, stream>>>(x, Wfrag, c_part, out);
}

// Round 9
// 107.113 us; speedup vs baseline: 1.9630x; 1.0120x over previous
//
#include <hip/hip_runtime.h>
#include <hip/hip_bf16.h>

// KAN harmonic-basis GEMM, v12: v8 compute + depth-3 counted-vmcnt DMA pipeline
// (T4: never drain vmcnt to 0 in the main loop; raw s_barrier).
// out[b,h] = sum_{d,f} basis(x[b,d])[f] * W[d,f,h] + sum_d b[d,h]
//
// f=0 + bias -> fp32 partials c_part[8][256], summed in GEMM epilogue.
// f=1..10    -> bf16 MFMA GEMM, M=16384, N=256, K=2560.
//
// v12 (v8/v11 A/B: occupancy 17->31% bought nothing; the stall is the
// __syncthreads vmcnt(0) drain every phase. Fix = counted wait + raw barrier):
//   - 256-thr blocks (4 waves = wr2 x wc2), v8's register-direct A-gen
//     (f32 sincos + Chebyshev, direct cvt_pk pack -- v11's fp16 path cost
//     +6us VALU and is reverted).
//   - 40 phases x 2 kt (16 KB each). Penta-buffer Bs[5][16KB] = 81,920 B
//     (2 blocks/CU); inner 5-phase loop unrolled so (q+3)%5 is compile-time,
//     outer dt loop NOT unrolled (I$ small).
//   - Per phase: issue stage(p+3) -> sched_barrier(0); s_waitcnt vmcnt(8);
//     s_barrier; sched_barrier(0) -> compute 2 kt from Bs[p%5].
//     Steady state: 8 loads (2 stages) stay in flight ACROSS the barrier.
//     vmcnt(8) retires exactly stage(p+1) (issued 2 phases earlier); stage(p)
//     was retired by the previous phase's wait, before the barrier that
//     publishes it -> read-after-write safe. Write-after-read: stage issued
//     at p targets buf[(p-2)%5], last read at p-2, and all waves passed the
//     p-1 barrier before any issue at p.
//   - x loads placed BEFORE the stage issue at dtile starts, so the
//     compiler's own x-wait is vmcnt(4), never 0.
//   - vmcnt(0) once after the loop (drain redundant tail DMAs).

#define BDIM 16384
#define DDIM 256
#define HOUT 256
#define NKT  80
#define BM 64
#define BN 128

typedef __bf16 bf16x8 __attribute__((ext_vector_type(8)));
typedef float floatx4 __attribute__((ext_vector_type(4)));

__device__ __forceinline__ unsigned short f2bf(float f) {
    unsigned int u = __float_as_uint(f);
    return (unsigned short)((u + 0x7FFFu + ((u >> 16) & 1u)) >> 16);
}

__device__ __forceinline__ unsigned int pkbf(float a, float b) {
    __hip_bfloat162 r = __float22bfloat162_rn(make_float2(a, b));
    return *reinterpret_cast<unsigned int*>(&r);
}

// grid 328 x 256 threads.
// blocks [0,320): kt = bid>>2, sub = bid&3:
//   Wfrag[kt][n=t][dd = sub*8 .. +8] = bf16(W[dtile*32+dd][kt%10+1][n])
// blocks [320,328): p = bid-320; c_part[p][h] = sum_{d in p*32..+32} W[d][0][h]+b[d][h]
__global__ void prep_kernel(const float* __restrict__ W, const float* __restrict__ bias,
                            unsigned short* __restrict__ Wfrag, float* __restrict__ c_part) {
    const int bid = blockIdx.x;
    const int t = threadIdx.x;
    if (bid < 4 * NKT) {
        const int kt = bid >> 2;
        const int sub = bid & 3;
        const int dtile = kt / 10;
        const int f = kt - dtile * 10 + 1;
        const int d0 = dtile * 32 + sub * 8;
        const float* wsrc = W + ((size_t)d0 * 11 + f) * 256 + t;
        union { unsigned short s[8]; int4 v; } buf;
#pragma unroll
        for (int dd = 0; dd < 8; ++dd)
            buf.s[dd] = f2bf(wsrc[(size_t)dd * 11 * 256]);
        *(int4*)(Wfrag + ((size_t)kt * 256 + t) * 32 + sub * 8) = buf.v;
    } else {
        const int p = bid - 4 * NKT;
        float acc = 0.f;
#pragma unroll
        for (int dd = 0; dd < 32; ++dd) {
            const int d = p * 32 + dd;
            acc += W[(size_t)(d * 11) * 256 + t] + bias[(size_t)d * 256 + t];
        }
        c_part[p * 256 + t] = acc;
    }
}

// Stage one 2-kt phase (16 KB) into lbuf. Chunk c in [0,16): ktl = c>>3,
// f = c&7 (16 cols). LDS dest linear (chunk*1024 + lane*16B); per-lane global
// source puts lane slot l at (col l&15, dgroup l>>4) -- exactly the MFMA
// B-frag slot read back. 4 waves x 4 chunks each (4 loads/wave/phase).
__device__ __forceinline__ void stage_phase(const unsigned short* __restrict__ Wfrag,
                                            unsigned short* lbuf, int ph,
                                            int h0, int wave, int l15, int koff) {
#pragma unroll
    for (int s = 0; s < 4; ++s) {
        const int c = wave * 4 + s;
        const int ktl = c >> 3;
        const int f = c & 7;
        const unsigned short* g = Wfrag + (size_t)(ph * 2 + ktl) * 8192
                                + (h0 + f * 16 + l15) * 32 + koff * 8;
        __builtin_amdgcn_global_load_lds((const void*)g, (void*)(lbuf + c * 512), 16, 0, 0);
    }
}

__global__ __launch_bounds__(256, 2)
void kan_gemm(const float* __restrict__ x, const unsigned short* __restrict__ Wfrag,
              const float* __restrict__ c_part, float* __restrict__ out) {
    __shared__ unsigned short Bs[5][2 * 8 * 512];   // 5 x 16,384 B = 81,920 B

    const int t = threadIdx.x;
    const int m0 = blockIdx.x * BM;
    const int h0 = blockIdx.y * BN;

    const int lane = t & 63;
    const int wave = t >> 6;         // 0..3
    const int wr = wave >> 1;        // row half (32 rows)
    const int wc = wave & 1;         // col half (64 cols)
    const int l15 = lane & 15;
    const int koff = lane >> 4;

    floatx4 acc[2][4];
#pragma unroll
    for (int i = 0; i < 2; ++i)
#pragma unroll
        for (int j = 0; j < 4; ++j)
            acc[i][j] = (floatx4){0.f, 0.f, 0.f, 0.f};

    // lane's x rows: i=0 -> m0 + wr*32 + l15, i=1 -> +16; d-slots koff*8..+8
    const float* xr0 = x + (size_t)(m0 + wr * 32 + l15) * DDIM + koff * 8;

    // prologue: stage phases 0,1,2 into buffers 0,1,2 (12 loads in flight)
    stage_phase(Wfrag, &Bs[0][0], 0, h0, wave, l15, koff);
    stage_phase(Wfrag, &Bs[1][0], 1, h0, wave, l15, koff);
    stage_phase(Wfrag, &Bs[2][0], 2, h0, wave, l15, koff);

    // Chebyshev state (f32, v8-proven numerics)
    float sc[16], cc[16], sp[16], cp[16], t2c[16];

#pragma unroll 1
    for (int dt = 0; dt < 8; ++dt) {
        // x for this dtile: issued BEFORE the q=0 stage so the compiler's
        // x-wait is vmcnt(4) (counting only stage(p+3)), never 0.
        const float4 xa0 = *(const float4*)(xr0 + dt * 32 + 0);
        const float4 xb0 = *(const float4*)(xr0 + dt * 32 + 4);
        const float4 xa1 = *(const float4*)(xr0 + 16 * DDIM + dt * 32 + 0);
        const float4 xb1 = *(const float4*)(xr0 + 16 * DDIM + dt * 32 + 4);

#pragma unroll
        for (int q = 0; q < 5; ++q) {
            // ---- issue stage(p+3) into buf[(q+3)%5] (clamped redundant tail) ----
            {
                int pt = dt * 5 + q + 3;
                if (pt > 39) pt = 39;
                stage_phase(Wfrag, &Bs[(q + 3) % 5][0], pt, h0, wave, l15, koff);
            }

            // ---- counted wait + publish barrier (T4: never vmcnt(0)) ----
            __builtin_amdgcn_sched_barrier(0);
            asm volatile("s_waitcnt vmcnt(8)" ::: "memory");
            __builtin_amdgcn_s_barrier();
            __builtin_amdgcn_sched_barrier(0);

            if (q == 0) {
                // ---- dtile start: sincos of 16 elems; Chebyshev init ----
                const float xv[16] = {xa0.x, xa0.y, xa0.z, xa0.w, xb0.x, xb0.y, xb0.z, xb0.w,
                                      xa1.x, xa1.y, xa1.z, xa1.w, xb1.x, xb1.y, xb1.z, xb1.w};
#pragma unroll
                for (int g = 0; g < 16; ++g) {
                    __sincosf(xv[g], &sc[g], &cc[g]);
                    t2c[g] = cc[g] + cc[g];
                    sp[g] = 0.f;
                    cp[g] = 1.f;
                }
            }

            // ---- compute 2 kt (harmonic k = q+1: sin then cos) ----
#pragma unroll
            for (int s = 0; s < 2; ++s) {
                const float* src = s ? cc : sc;

                union { unsigned int u[4]; bf16x8 v; } a0, a1;
#pragma unroll
                for (int p = 0; p < 4; ++p) {
                    a0.u[p] = pkbf(src[2 * p], src[2 * p + 1]);
                    a1.u[p] = pkbf(src[8 + 2 * p], src[8 + 2 * p + 1]);
                }

                const unsigned short* fb = &Bs[q][(s * 8 + wc * 4) * 512 + lane * 8];
                const bf16x8 b0 = *(const bf16x8*)(fb);
                const bf16x8 b1 = *(const bf16x8*)(fb + 512);
                const bf16x8 b2 = *(const bf16x8*)(fb + 1024);
                const bf16x8 b3 = *(const bf16x8*)(fb + 1536);

                acc[0][0] = __builtin_amdgcn_mfma_f32_16x16x32_bf16(a0.v, b0, acc[0][0], 0, 0, 0);
                acc[1][0] = __builtin_amdgcn_mfma_f32_16x16x32_bf16(a1.v, b0, acc[1][0], 0, 0, 0);
                acc[0][1] = __builtin_amdgcn_mfma_f32_16x16x32_bf16(a0.v, b1, acc[0][1], 0, 0, 0);
                acc[1][1] = __builtin_amdgcn_mfma_f32_16x16x32_bf16(a1.v, b1, acc[1][1], 0, 0, 0);
                acc[0][2] = __builtin_amdgcn_mfma_f32_16x16x32_bf16(a0.v, b2, acc[0][2], 0, 0, 0);
                acc[1][2] = __builtin_amdgcn_mfma_f32_16x16x32_bf16(a1.v, b2, acc[1][2], 0, 0, 0);
                acc[0][3] = __builtin_amdgcn_mfma_f32_16x16x32_bf16(a0.v, b3, acc[0][3], 0, 0, 0);
                acc[1][3] = __builtin_amdgcn_mfma_f32_16x16x32_bf16(a1.v, b3, acc[1][3], 0, 0, 0);

                // advance harmonic after the cos emit (except k=5)
                if (s == 1 && q < 4) {
#pragma unroll
                    for (int g = 0; g < 16; ++g) {
                        const float ns = t2c[g] * sc[g] - sp[g];
                        const float nc = t2c[g] * cc[g] - cp[g];
                        sp[g] = sc[g]; cp[g] = cc[g];
                        sc[g] = ns;   cc[g] = nc;
                    }
                }
            }
        }
    }

    // drain redundant tail DMAs before reusing/ending
    asm volatile("s_waitcnt vmcnt(0)" ::: "memory");

    // ---- epilogue: C/D layout col=lane&15, row=(lane>>4)*4+reg ----
    float cj[4];
#pragma unroll
    for (int j = 0; j < 4; ++j) {
        const int col = h0 + wc * 64 + j * 16 + l15;
        float s = 0.f;
#pragma unroll
        for (int q = 0; q < 8; ++q) s += c_part[q * 256 + col];
        cj[j] = s;
    }
#pragma unroll
    for (int i = 0; i < 2; ++i) {
        const int row0 = m0 + wr * 32 + i * 16 + koff * 4;
#pragma unroll
        for (int j = 0; j < 4; ++j) {
            const int col = h0 + wc * 64 + j * 16 + l15;
#pragma unroll
            for (int r = 0; r < 4; ++r)
                out[(size_t)(row0 + r) * HOUT + col] = acc[i][j][r] + cj[j];
        }
    }
}

extern "C" void kernel_launch(void* const* d_in, const int* in_sizes, int n_in,
                              void* d_out, int out_size, void* d_ws, size_t ws_size,
                              hipStream_t stream) {
    const float* x = (const float*)d_in[0];
    const float* W = (const float*)d_in[1];
    const float* b = (const float*)d_in[2];
    float* out = (float*)d_out;

    unsigned short* Wfrag = (unsigned short*)d_ws;                      // 1,310,720 B
    float* c_part = (float*)((char*)d_ws + (size_t)NKT * 256 * 32 * 2); // 8 KB

    prep_kernel<<<4 * NKT + 8, 256, 0, stream>>>(W, b, Wfrag, c_part);
    kan_gemm<<<dim3(BDIM / BM, HOUT / BN), 256, 0, stream>>>(x, Wfrag, c_part, out);
}